// Round 5
// baseline (1532.681 us; speedup 1.0000x reference)
//
#include <hip/hip_runtime.h>
#include <hip/hip_bf16.h>

// T=4096, B=8, E=512. Dual EMA (pos/neg split) along T.
//   pb = sigmoid(raw_pos_beta[e]); nb = sigmoid(raw_neg_beta[e])
//   mem_p[t] = pb*mem_p[t-1] + max(x,0)*(1-pb)
//   mem_n[t] = nb*mem_n[t-1] + min(x,0)*(1-nb)
//   out[t,b,e] = mem_p + mem_n
//
// ROUND-5: dtype-universal diagnostic. Rounds 1-4 (bf16 interpretation,
// incl. a memset sentinel) all left the checked buffer looking untouched.
// The reference is float32; the bf16 inference rested on literal label text.
// This kernel probes the real dtype at runtime (fp32 data read as bf16
// half-words yields huge magnitudes; true bf16 N(0,1) stays < ~6) and then
// runs an exact serial scan in whichever format is present. One thread per
// (b,e) channel; correctness-first, optimize once something executes.

#define T_DIM 4096
#define B_DIM 8
#define E_DIM 512
#define BE (B_DIM * E_DIM)   // 4096 channels; t-stride in elements

__global__ void ParallelDLIEMA_17789754541002_kernel(
        const unsigned short* x,
        const unsigned short* rp,
        const unsigned short* rn,
        unsigned short* out,
        int n) {
    int gtid = blockIdx.x * blockDim.x + threadIdx.x;
    if (gtid >= n) return;
    int e = gtid & (E_DIM - 1);

    // Runtime dtype probe (uniform across threads): scan 512 half-words of x.
    bool is_fp32 = false;
    for (int j = 0; j < 512; j++) {
        float v = __uint_as_float(((unsigned int)x[j]) << 16);
        if (fabsf(v) > 1.0e4f) is_fp32 = true;
    }

    float rpf, rnf;
    if (is_fp32) {
        rpf = ((const float*)rp)[e];
        rnf = ((const float*)rn)[e];
    } else {
        rpf = __uint_as_float(((unsigned int)rp[e]) << 16);
        rnf = __uint_as_float(((unsigned int)rn[e]) << 16);
    }
    float pb = 1.0f / (1.0f + __expf(-rpf));
    float nb = 1.0f / (1.0f + __expf(-rnf));
    float omp = 1.0f - pb, omn = 1.0f - nb;
    float mp = 0.0f, mn = 0.0f;

    if (is_fp32) {
        const float* xf = (const float*)x;
        float* of = (float*)out;
        for (int t = 0; t < T_DIM; t++) {
            float f = xf[t * BE + gtid];
            mp = pb * mp + fmaxf(f, 0.0f) * omp;
            mn = nb * mn + fminf(f, 0.0f) * omn;
            of[t * BE + gtid] = mp + mn;
        }
    } else {
        for (int t = 0; t < T_DIM; t++) {
            float f = __uint_as_float(((unsigned int)x[t * BE + gtid]) << 16);
            mp = pb * mp + fmaxf(f, 0.0f) * omp;
            mn = nb * mn + fminf(f, 0.0f) * omn;
            float o = mp + mn;
            unsigned int ub = __float_as_uint(o);
            out[t * BE + gtid] =
                (unsigned short)((ub + 0x7fffu + ((ub >> 16) & 1u)) >> 16); // RNE
        }
    }
}

extern "C" void kernel_launch(void* const* d_in, const int* in_sizes, int n_in,
                              void* d_out, int out_size, void* d_ws, size_t ws_size,
                              hipStream_t stream) {
    const unsigned short* x  = (const unsigned short*)d_in[0];
    const unsigned short* rp = (const unsigned short*)d_in[1];
    const unsigned short* rn = (const unsigned short*)d_in[2];
    unsigned short* out = (unsigned short*)d_out;
    int n = BE;  // one thread per (b,e) channel, serial scan over T
    ParallelDLIEMA_17789754541002_kernel<<<(n + 255) / 256, 256, 0, stream>>>(
        x, rp, rn, out, n);
}

// Round 6
// 136.646 us; speedup vs baseline: 11.2165x; 11.2165x over previous
//
#include <hip/hip_runtime.h>

// T=4096, B=8, E=512. Dual EMA (pos/neg split) along T. fp32 in/out
// (confirmed round 5: WRITE_SIZE == out_size*4 and absmax 3.9e-3 passed).
//   pb = sigmoid(raw_pos_beta[e]); nb = sigmoid(raw_neg_beta[e])
//   mem_p[t] = pb*mem_p[t-1] + max(x,0)*(1-pb)
//   mem_n[t] = nb*mem_n[t-1] + min(x,0)*(1-nb)
//   out[t,b,e] = mem_p + mem_n
//
// Chunked scan, C=256 chunks of L=16 along T:
//   K1: per-(chunk,b,e) local finals with zero init -> stored IN d_out at
//       t = c*16+0 (pos final) and t = c*16+1 (neg final), fp32.
//   K2: per-(state,b,e) serial carry scan across 256 chunks, replaces each
//       chunk's final with the carry INTO that chunk.
//   K3: re-runs local scans seeded with the carries, overwrites the whole
//       output (including the carry slots). Stream-ordered => race-free.
// No d_ws use.

#define T_DIM 4096
#define B_DIM 8
#define E_DIM 512
#define CHUNK_L 16
#define NCHUNK (T_DIM / CHUNK_L)   // 256
#define BE (B_DIM * E_DIM)         // 4096 elements per t-step

__device__ __forceinline__ float sigmoidf_(float x) { return 1.0f / (1.0f + __expf(-x)); }

// K1: 262144 threads; thread = (c, b, e4). 16 strided float4 loads of x.
__global__ __launch_bounds__(256) void ParallelDLIEMA_17789754541002_kernel(
        const float* __restrict__ x,
        const float* __restrict__ rp,
        const float* __restrict__ rn,
        float* __restrict__ out) {
    int gtid = blockIdx.x * 256 + threadIdx.x;
    int e4 = gtid & 127;          // E/4 = 128
    int b  = (gtid >> 7) & 7;
    int c  = gtid >> 10;          // 0..255
    int e  = e4 * 4;

    float4 rp4 = *(const float4*)(rp + e);
    float4 rn4 = *(const float4*)(rn + e);
    float bp[4] = {sigmoidf_(rp4.x), sigmoidf_(rp4.y), sigmoidf_(rp4.z), sigmoidf_(rp4.w)};
    float bn[4] = {sigmoidf_(rn4.x), sigmoidf_(rn4.y), sigmoidf_(rn4.z), sigmoidf_(rn4.w)};

    float fp4[4] = {0.f, 0.f, 0.f, 0.f};
    float fn4[4] = {0.f, 0.f, 0.f, 0.f};
    int base = c * CHUNK_L * BE + b * E_DIM + e;
    #pragma unroll
    for (int k = 0; k < CHUNK_L; k++) {
        float4 xv = *(const float4*)(x + base + k * BE);
        float f[4] = {xv.x, xv.y, xv.z, xv.w};
        #pragma unroll
        for (int j = 0; j < 4; j++) {
            fp4[j] = bp[j] * fp4[j] + fmaxf(f[j], 0.f) * (1.0f - bp[j]);
            fn4[j] = bn[j] * fn4[j] + fminf(f[j], 0.f) * (1.0f - bn[j]);
        }
    }
    *(float4*)(out + base + 0 * BE) = make_float4(fp4[0], fp4[1], fp4[2], fp4[3]);
    *(float4*)(out + base + 1 * BE) = make_float4(fn4[0], fn4[1], fn4[2], fn4[3]);
}

// K2: 8192 threads; thread = (s, b, e). Carry scan across chunks.
__global__ __launch_bounds__(256) void k_carry(const float* __restrict__ rp,
                                               const float* __restrict__ rn,
                                               float* __restrict__ out) {
    int gtid = blockIdx.x * 256 + threadIdx.x;
    int e = gtid & 511;
    int b = (gtid >> 9) & 7;
    int s = gtid >> 12;                        // 0 = pos, 1 = neg
    float beta = sigmoidf_(s ? rn[e] : rp[e]);
    float bl = beta * beta; bl = bl * bl; bl = bl * bl; bl = bl * bl;  // beta^16

    float* p = out + s * BE + b * E_DIM + e;   // slot t = c*16 + s
    float carry = 0.f;
    for (int g = 0; g < NCHUNK / 16; g++) {
        float fv[16];
        #pragma unroll
        for (int u = 0; u < 16; u++) fv[u] = p[(g * 16 + u) * (CHUNK_L * BE)];
        #pragma unroll
        for (int u = 0; u < 16; u++) {
            p[(g * 16 + u) * (CHUNK_L * BE)] = carry;   // carry INTO chunk
            carry = bl * carry + fv[u];
        }
    }
}

// K3: same shape as K1; seed from carry slots, write final output.
__global__ __launch_bounds__(256) void k_out(const float* __restrict__ x,
                                             const float* __restrict__ rp,
                                             const float* __restrict__ rn,
                                             float* __restrict__ out) {
    int gtid = blockIdx.x * 256 + threadIdx.x;
    int e4 = gtid & 127;
    int b  = (gtid >> 7) & 7;
    int c  = gtid >> 10;
    int e  = e4 * 4;

    float4 rp4 = *(const float4*)(rp + e);
    float4 rn4 = *(const float4*)(rn + e);
    float bp[4] = {sigmoidf_(rp4.x), sigmoidf_(rp4.y), sigmoidf_(rp4.z), sigmoidf_(rp4.w)};
    float bn[4] = {sigmoidf_(rn4.x), sigmoidf_(rn4.y), sigmoidf_(rn4.z), sigmoidf_(rn4.w)};

    int base = c * CHUNK_L * BE + b * E_DIM + e;
    float4 cp = *(const float4*)(out + base + 0 * BE);
    float4 cn = *(const float4*)(out + base + 1 * BE);
    float lp[4] = {cp.x, cp.y, cp.z, cp.w};
    float ln[4] = {cn.x, cn.y, cn.z, cn.w};

    #pragma unroll
    for (int k = 0; k < CHUNK_L; k++) {
        float4 xv = *(const float4*)(x + base + k * BE);
        float f[4] = {xv.x, xv.y, xv.z, xv.w};
        float o[4];
        #pragma unroll
        for (int j = 0; j < 4; j++) {
            lp[j] = bp[j] * lp[j] + fmaxf(f[j], 0.f) * (1.0f - bp[j]);
            ln[j] = bn[j] * ln[j] + fminf(f[j], 0.f) * (1.0f - bn[j]);
            o[j] = lp[j] + ln[j];
        }
        *(float4*)(out + base + k * BE) = make_float4(o[0], o[1], o[2], o[3]);
    }
}

extern "C" void kernel_launch(void* const* d_in, const int* in_sizes, int n_in,
                              void* d_out, int out_size, void* d_ws, size_t ws_size,
                              hipStream_t stream) {
    const float* x  = (const float*)d_in[0];
    const float* rp = (const float*)d_in[1];
    const float* rn = (const float*)d_in[2];
    float* out = (float*)d_out;

    // K1: 256 chunks * 8 b * 128 e-quads = 262144 threads
    ParallelDLIEMA_17789754541002_kernel<<<1024, 256, 0, stream>>>(x, rp, rn, out);
    // K2: 2 states * 8 b * 512 e = 8192 threads
    k_carry<<<32, 256, 0, stream>>>(rp, rn, out);
    // K3: same shape as K1
    k_out<<<1024, 256, 0, stream>>>(x, rp, rn, out);
}